// Round 4
// baseline (569.738 us; speedup 1.0000x reference)
//
#include <hip/hip_runtime.h>
#include <hip/hip_bf16.h>

#define B_ROWS   4096
#define L_LABELS 100000
#define L_PAD    100032   // 1563 * 64, padded with zero rows
#define PADROWS  32       // L_PAD - L_LABELS
#define D_DIM    256
#define TOPK     5
#define SLABN    64       // labels per slab
#define NSLAB    1563     // L_PAD / SLABN
#define NGROUP   8        // N-groups == XCD count
#define SLABBYTES 32768   // SLABN * D_DIM * 2
#define HALFB    16384    // lo-K half staged in LDS per slab

typedef __bf16 bf16x8 __attribute__((ext_vector_type(8)));
typedef __bf16 bf16x4 __attribute__((ext_vector_type(4)));
typedef float  f32x4  __attribute__((ext_vector_type(4)));

__device__ __forceinline__ void async16(const void* g, void* l) {
    __builtin_amdgcn_global_load_lds(
        (const __attribute__((address_space(1))) unsigned int*)g,
        (__attribute__((address_space(3))) unsigned int*)l,
        16, 0, 0);
}

// ---------------------------------------------------------------------------
// fp32 -> bf16 converters
// ---------------------------------------------------------------------------
__global__ void convertP_kernel(const float* __restrict__ src,
                                __hip_bfloat16* __restrict__ dst) {
    size_t i = ((size_t)blockIdx.x * blockDim.x + threadIdx.x) * 8;
    float4 a = *(const float4*)(src + i);
    float4 b = *(const float4*)(src + i + 4);
    bf16x8 v = {(__bf16)a.x, (__bf16)a.y, (__bf16)a.z, (__bf16)a.w,
                (__bf16)b.x, (__bf16)b.y, (__bf16)b.z, (__bf16)b.w};
    *(bf16x8*)((__bf16*)dst + i) = v;
}

__global__ void convertL_kernel(const float* __restrict__ src,
                                __hip_bfloat16* __restrict__ dst) {
    size_t i = ((size_t)blockIdx.x * blockDim.x + threadIdx.x) * 8;
    bf16x8 v;
    if (i < (size_t)L_LABELS * D_DIM) {
        float4 a = *(const float4*)(src + i);
        float4 b = *(const float4*)(src + i + 4);
        v = (bf16x8){(__bf16)a.x, (__bf16)a.y, (__bf16)a.z, (__bf16)a.w,
                     (__bf16)b.x, (__bf16)b.y, (__bf16)b.z, (__bf16)b.w};
    } else {
        v = (bf16x8){(__bf16)0.f, (__bf16)0.f, (__bf16)0.f, (__bf16)0.f,
                     (__bf16)0.f, (__bf16)0.f, (__bf16)0.f, (__bf16)0.f};
    }
    *(bf16x8*)((__bf16*)dst + i) = v;
}

// ---------------------------------------------------------------------------
// Kernel 1: per-row threshold s_t (bf16-rounded inputs) + zero counters.
// ---------------------------------------------------------------------------
__global__ void prep_kernel(const float* __restrict__ P,
                            const float* __restrict__ Lab,
                            const int*   __restrict__ labels,
                            float* __restrict__ s_t,
                            int*   __restrict__ counts) {
    int gwave = (blockIdx.x * blockDim.x + threadIdx.x) >> 6;
    int lane  = threadIdx.x & 63;
    if (gwave >= B_ROWS) return;
    int t = labels[gwave];
    const float4* p4 = (const float4*)(P + (size_t)gwave * D_DIM);
    const float4* l4 = (const float4*)(Lab + (size_t)t * D_DIM);
    float4 a = p4[lane];
    float4 b = l4[lane];
    float sum = 0.f;
    sum += (float)(__bf16)a.x * (float)(__bf16)b.x;
    sum += (float)(__bf16)a.y * (float)(__bf16)b.y;
    sum += (float)(__bf16)a.z * (float)(__bf16)b.z;
    sum += (float)(__bf16)a.w * (float)(__bf16)b.w;
    #pragma unroll
    for (int m = 1; m < 64; m <<= 1) sum += __shfl_xor(sum, m, 64);
    if (lane == 0) {
        s_t[gwave]    = sum;
        counts[gwave] = 0;
    }
}

// ---------------------------------------------------------------------------
// Kernel 2 (v7): dual-path B streaming.
//
// v6 post-mortem: LDS unit ~85-90% busy (reads 400K cyc + DMA-write side
// ~120K of the 616K-cyc kernel). B-from-LDS traffic is structurally
// 512B/row-work (invariant in decomposition); M_wave=32 is the register
// optimum. So v7 removes HALF the B traffic from the LDS unit entirely:
//   - K in [0,128): staged in LDS via global_load_lds (16KB/slab, dbuf)
//   - K in [128,256): per-wave global_load_dwordx4 straight from Lb
//     (slab is L1/L2-resident; loads issue right after the barrier and
//     are consumed after the 4 LDS-kb MFMAs, hiding L1/L2 latency)
// Two balanced pipes (~1350 cyc LDS, ~1500 cyc VMEM per CU-slab) replace
// one saturated one. LDS/block drops 64->32KB.
// ---------------------------------------------------------------------------
#define CBM 64

__global__ __launch_bounds__(512, 4)
void count_kernel_v7(const __hip_bfloat16* __restrict__ Pb,
                     const __hip_bfloat16* __restrict__ Lb,
                     const int*   __restrict__ labels,
                     const float* __restrict__ s_t,
                     int* __restrict__ counts) {
    __shared__ __align__(16) __bf16 Bs[2 * SLABN * 128];   // 2 x 16 KB

    const int group = blockIdx.x;          // 0..7 -> XCD via %8 dispatch
    const int Mbase = blockIdx.y * CBM;
    const int tid   = threadIdx.x;
    const int wave  = tid >> 6;            // 0..7
    const int lane  = tid & 63;
    const int wm    = wave >> 2;           // 0..1 : 32-row half
    const int wn    = wave & 3;            // 0..3 : 16-label quarter
    const int quad  = lane >> 4;           // 0..3
    const int cc    = lane & 15;           // 0..15
    const int R     = wn * 16 + cc;        // B label-row this lane reads

    const int s0 = (group * NSLAB) / NGROUP;
    const int s1 = ((group + 1) * NSLAB) / NGROUP;

    // DMA source offset (lo half). Slot s = j*512+tid -> row=s>>4, qc=s&15.
    // XOR chunk swizzle: LDS slot (row,qc) holds global chunk
    // (qc&8)|((qc^row)&7); row&7 is j-invariant so offset j=1 = j=0 + 16384.
    const int row0 = tid >> 4;             // 0..31
    const int qc0  = tid & 15;
    const int gc0  = (qc0 & 8) | ((qc0 ^ row0) & 7);
    const int dma0 = row0 * 512 + gc0 * 16;
    const int ldsw = wave * 1024;          // wave-uniform LDS base (bytes)

    // LDS read offsets for kb 0..3 (inverse swizzle: qc* = (ci&8)|((ci^R)&7),
    // R&7 == cc&7). Row stride in the half-buffer is 256 B.
    int lds_off[4];
    #pragma unroll
    for (int kb = 0; kb < 4; ++kb) {
        int ci  = kb * 4 + quad;
        int gcr = (ci & 8) | ((ci ^ cc) & 7);
        lds_off[kb] = R * 256 + gcr * 16;
    }

    const char* gs = (const char*)Lb + (size_t)s0 * SLABBYTES;

    // ---- issue DMA for first slab's lo-half into buffer 0 ----
    async16(gs + dma0,         (char*)Bs + ldsw);
    async16(gs + dma0 + HALFB, (char*)Bs + 8192 + ldsw);

    // ---- load stationary A fragments: 32 rows x K=256 per wave ----
    bf16x8 af[2][8];
    #pragma unroll
    for (int mi = 0; mi < 2; ++mi) {
        int row = Mbase + wm * 32 + mi * 16 + cc;
        const __bf16* ap = (const __bf16*)Pb + (size_t)row * D_DIM + quad * 8;
        #pragma unroll
        for (int kb = 0; kb < 8; ++kb)
            af[mi][kb] = *(const bf16x8*)(ap + kb * 32);
    }

    // ---- per-row threshold / label (C/D rows: quad*4 + r) ----
    float sr[2][4];
    int   tr[2][4];
    #pragma unroll
    for (int mi = 0; mi < 2; ++mi)
        #pragma unroll
        for (int r = 0; r < 4; ++r) {
            int row = Mbase + wm * 32 + mi * 16 + quad * 4 + r;
            sr[mi][r] = s_t[row];
            tr[mi][r] = labels[row];
        }

    int cnt[2][4] = {};

    for (int s = s0, it = 0; s < s1; ++s, ++it) {
        __syncthreads();   // lo-half of slab s staged; buffers safe to reuse

        // current slab hi-half (K 128..255) straight from global (L1/L2).
        // Issued first (oldest); consumed after the 4 LDS-kb MFMAs.
        bf16x8 bg[4];
        {
            const char* ghb = gs + (size_t)R * 512 + 256 + quad * 16;
            #pragma unroll
            for (int kb = 0; kb < 4; ++kb)
                bg[kb] = *(const bf16x8*)(ghb + kb * 64);
        }

        // prefetch next slab's lo-half DMA into the other buffer
        if (s + 1 < s1) {
            const char* gn = gs + SLABBYTES;
            char* lb = (char*)Bs + (size_t)(~it & 1) * HALFB + ldsw;
            async16(gn + dma0,         lb);
            async16(gn + dma0 + HALFB, lb + 8192);
        }

        const char* bp = (const char*)Bs + (size_t)(it & 1) * HALFB;

        f32x4 acc[2] = {};
        #pragma unroll
        for (int kb = 0; kb < 4; ++kb) {
            bf16x8 b = *(const bf16x8*)(bp + lds_off[kb]);
            acc[0] = __builtin_amdgcn_mfma_f32_16x16x32_bf16(
                af[0][kb], b, acc[0], 0, 0, 0);
            acc[1] = __builtin_amdgcn_mfma_f32_16x16x32_bf16(
                af[1][kb], b, acc[1], 0, 0, 0);
        }
        #pragma unroll
        for (int kb = 0; kb < 4; ++kb) {
            acc[0] = __builtin_amdgcn_mfma_f32_16x16x32_bf16(
                af[0][4 + kb], bg[kb], acc[0], 0, 0, 0);
            acc[1] = __builtin_amdgcn_mfma_f32_16x16x32_bf16(
                af[1][4 + kb], bg[kb], acc[1], 0, 0, 0);
        }

        // epilogue: accumulate beat counts in registers
        int n = s * SLABN + wn * 16 + cc;
        #pragma unroll
        for (int mi = 0; mi < 2; ++mi)
            #pragma unroll
            for (int r = 0; r < 4; ++r) {
                float sv = acc[mi][r];
                bool beat = (n != tr[mi][r]) &&
                            (sv > sr[mi][r] ||
                             (sv == sr[mi][r] && n < tr[mi][r]));
                cnt[mi][r] += beat ? 1 : 0;
            }

        gs += SLABBYTES;
    }

    // ---- reduce over the 16 cc lanes, one atomic per (wave, quad, mi, r) ----
    #pragma unroll
    for (int mi = 0; mi < 2; ++mi)
        #pragma unroll
        for (int r = 0; r < 4; ++r) {
            int v = cnt[mi][r];
            v += __shfl_xor(v, 1, 64);
            v += __shfl_xor(v, 2, 64);
            v += __shfl_xor(v, 4, 64);
            v += __shfl_xor(v, 8, 64);
            if (cc == 0) {
                int row = Mbase + wm * 32 + mi * 16 + quad * 4 + r;
                atomicAdd(&counts[row], v);
            }
        }
}

// ---------------------------------------------------------------------------
// Kernel 2 (fallback, R1 path) — only if ws too small for bf16 copies.
// ---------------------------------------------------------------------------
#define FBM 128
#define FBN 128
#define FBK 32
#define KPAD 40

__global__ __launch_bounds__(256)
void count_kernel_slow(const float* __restrict__ P,
                       const float* __restrict__ Lab,
                       const int*   __restrict__ labels,
                       const float* __restrict__ s_t,
                       int* __restrict__ counts) {
    __shared__ __align__(16) __bf16 As[FBM][KPAD];
    __shared__ __align__(16) __bf16 Bs[FBN][KPAD];

    const int Nbase = blockIdx.x * FBN;
    const int Mbase = blockIdx.y * FBM;
    const int tid  = threadIdx.x;
    const int lane = tid & 63;
    const int wave = tid >> 6;
    const int wm = wave >> 1;
    const int wn = wave & 1;
    const int quad = lane >> 4;
    const int c    = lane & 15;

    const int srow  = tid >> 1;
    const int skoff = (tid & 1) * 16;
    const int brow_g = min(Nbase + srow, L_LABELS - 1);

    f32x4 acc[4][4] = {};

    for (int Kb = 0; Kb < D_DIM; Kb += FBK) {
        const float* gA = P   + (size_t)(Mbase + srow) * D_DIM + Kb + skoff;
        const float* gB = Lab + (size_t)brow_g        * D_DIM + Kb + skoff;
        #pragma unroll
        for (int i = 0; i < 4; ++i) {
            float4 va = *(const float4*)(gA + i * 4);
            float4 vb = *(const float4*)(gB + i * 4);
            *(bf16x4*)&As[srow][skoff + i * 4] =
                (bf16x4){(__bf16)va.x, (__bf16)va.y, (__bf16)va.z, (__bf16)va.w};
            *(bf16x4*)&Bs[srow][skoff + i * 4] =
                (bf16x4){(__bf16)vb.x, (__bf16)vb.y, (__bf16)vb.z, (__bf16)vb.w};
        }
        __syncthreads();

        bf16x8 afr[4], bfr[4];
        #pragma unroll
        for (int mi = 0; mi < 4; ++mi)
            afr[mi] = *(const bf16x8*)&As[wm * 64 + mi * 16 + c][quad * 8];
        #pragma unroll
        for (int ni = 0; ni < 4; ++ni)
            bfr[ni] = *(const bf16x8*)&Bs[wn * 64 + ni * 16 + c][quad * 8];

        #pragma unroll
        for (int mi = 0; mi < 4; ++mi)
            #pragma unroll
            for (int ni = 0; ni < 4; ++ni)
                acc[mi][ni] = __builtin_amdgcn_mfma_f32_16x16x32_bf16(
                    afr[mi], bfr[ni], acc[mi][ni], 0, 0, 0);
        __syncthreads();
    }

    #pragma unroll
    for (int mi = 0; mi < 4; ++mi) {
        int rowb = Mbase + wm * 64 + mi * 16 + quad * 4;
        #pragma unroll
        for (int r = 0; r < 4; ++r) {
            int   row = rowb + r;
            float st  = s_t[row];
            int   t   = labels[row];
            int   cnt = 0;
            #pragma unroll
            for (int ni = 0; ni < 4; ++ni) {
                int   n = Nbase + wn * 64 + ni * 16 + c;
                float s = acc[mi][ni][r];
                bool beat = (n < L_LABELS) && (n != t) &&
                            (s > st || (s == st && n < t));
                cnt += beat ? 1 : 0;
            }
            cnt += __shfl_xor(cnt, 1, 64);
            cnt += __shfl_xor(cnt, 2, 64);
            cnt += __shfl_xor(cnt, 4, 64);
            cnt += __shfl_xor(cnt, 8, 64);
            if (c == 0 && cnt) atomicAdd(&counts[row], cnt);
        }
    }
}

// ---------------------------------------------------------------------------
// Kernel 3: accuracy = mean(adjusted_counts[b] < TOPK).
// ---------------------------------------------------------------------------
__global__ void finalize_kernel(const int* __restrict__ counts,
                                const float* __restrict__ s_t,
                                float* __restrict__ out,
                                int pad_correct) {
    __shared__ int sdata[4];
    int tid = threadIdx.x;
    int local = 0;
    for (int i = tid; i < B_ROWS; i += 256) {
        int c = counts[i];
        if (pad_correct && s_t[i] < 0.0f) c -= PADROWS;
        local += (c < TOPK) ? 1 : 0;
    }
    #pragma unroll
    for (int m = 1; m < 64; m <<= 1) local += __shfl_xor(local, m, 64);
    if ((tid & 63) == 0) sdata[tid >> 6] = local;
    __syncthreads();
    if (tid == 0)
        out[0] = (float)(sdata[0] + sdata[1] + sdata[2] + sdata[3]) /
                 (float)B_ROWS;
}

extern "C" void kernel_launch(void* const* d_in, const int* in_sizes, int n_in,
                              void* d_out, int out_size, void* d_ws, size_t ws_size,
                              hipStream_t stream) {
    const float* P      = (const float*)d_in[0];
    const float* Lab    = (const float*)d_in[1];
    const int*   labels = (const int*)d_in[2];
    float* out = (float*)d_out;

    float* s_t    = (float*)d_ws;
    int*   counts = (int*)((char*)d_ws + 16384);

    prep_kernel<<<dim3(B_ROWS / 4), 256, 0, stream>>>(P, Lab, labels, s_t, counts);

    const size_t pb_off = 32768;
    const size_t lb_off = pb_off + (size_t)B_ROWS * D_DIM * 2;  // 2 MB
    const size_t need   = lb_off + (size_t)L_PAD * D_DIM * 2;   // ~51 MB

    int fast = (ws_size >= need) ? 1 : 0;
    if (fast) {
        __hip_bfloat16* Pb = (__hip_bfloat16*)((char*)d_ws + pb_off);
        __hip_bfloat16* Lb = (__hip_bfloat16*)((char*)d_ws + lb_off);
        convertP_kernel<<<dim3((B_ROWS * D_DIM) / 2048), 256, 0, stream>>>(P, Pb);
        convertL_kernel<<<dim3(((size_t)L_PAD * D_DIM) / 2048), 256, 0, stream>>>(Lab, Lb);
        count_kernel_v7<<<dim3(NGROUP, B_ROWS / CBM), 512, 0, stream>>>(
            Pb, Lb, labels, s_t, counts);
    } else {
        dim3 grid((L_LABELS + FBN - 1) / FBN, B_ROWS / FBM);
        count_kernel_slow<<<grid, 256, 0, stream>>>(P, Lab, labels, s_t, counts);
    }

    finalize_kernel<<<1, 256, 0, stream>>>(counts, s_t, out, fast);
}